// Round 1
// baseline (645.208 us; speedup 1.0000x reference)
//
#include <hip/hip_runtime.h>
#include <math.h>

// LuongAttention: B=64, S=2048, D=1024
//   sims[b,s] = dot(enc[b,s,:], hid[b,:]); mask -> -inf; softmax over s;
//   out[b,d]  = sum_s attn[b,s] * enc[b,s,d]
// Flash-style single pass over enc_out + wave-uniform skip of masked rows
// (masked rows contribute nothing -> never fetch their 4KB row).

constexpr int Bc = 64;
constexpr int Sc = 2048;
constexpr int Dc = 1024;

// Block = 256 threads = 4 waves. Each wave owns a contiguous row range with
// online-softmax state entirely in registers:
//   lane j holds d-slots {4j..4j+3} at offsets +0,+256,+512,+768  (4 x float4)
// Wave states are merged once per block through LDS.
__global__ __launch_bounds__(256, 4)
void attn_partial(const int* __restrict__ mask,    // [B,S] 0/1 (1 = masked)
                  const float* __restrict__ enc,   // [B,S,D]
                  const float* __restrict__ hid,   // [B,D]
                  float* __restrict__ o_part,      // [B,SPLIT,D] (unnormalized)
                  float* __restrict__ ml_part,     // [B,SPLIT,2] (M, L)
                  float* __restrict__ out_final,   // [B,D] when SPLIT==1, else null
                  int SPLIT, int CHUNK)
{
    __shared__ float so[4][Dc];   // 16 KB: per-wave unnormalized context
    __shared__ float sm[4], sl[4];

    const int split = blockIdx.x;
    const int b     = blockIdx.y;
    const int tid   = threadIdx.x;
    const int wid   = tid >> 6;
    const int lane  = tid & 63;
    const int d0    = lane << 2;

    const float* hb = hid + (size_t)b * Dc;
    const float4 h0 = *(const float4*)(hb + d0);
    const float4 h1 = *(const float4*)(hb + d0 + 256);
    const float4 h2 = *(const float4*)(hb + d0 + 512);
    const float4 h3 = *(const float4*)(hb + d0 + 768);

    float4 o0 = make_float4(0.f,0.f,0.f,0.f);
    float4 o1 = o0, o2 = o0, o3 = o0;
    float m = -INFINITY, l = 0.f;

    const int rpw  = CHUNK >> 2;                  // rows per wave
    const int sbeg = split * CHUNK + wid * rpw;
    const int* mrow = mask + (size_t)b * Sc;
    const float* ebase = enc + ((size_t)b * Sc + (size_t)sbeg) * Dc;

    for (int i = 0; i < rpw; ++i) {
        if (mrow[sbeg + i]) continue;             // wave-uniform skip: no fetch
        const float* row = ebase + (size_t)i * Dc;
        const float4 x0 = *(const float4*)(row + d0);
        const float4 x1 = *(const float4*)(row + d0 + 256);
        const float4 x2 = *(const float4*)(row + d0 + 512);
        const float4 x3 = *(const float4*)(row + d0 + 768);

        float p = x0.x*h0.x + x0.y*h0.y + x0.z*h0.z + x0.w*h0.w;
        p      += x1.x*h1.x + x1.y*h1.y + x1.z*h1.z + x1.w*h1.w;
        p      += x2.x*h2.x + x2.y*h2.y + x2.z*h2.z + x2.w*h2.w;
        p      += x3.x*h3.x + x3.y*h3.y + x3.z*h3.z + x3.w*h3.w;
        #pragma unroll
        for (int off = 32; off > 0; off >>= 1)
            p += __shfl_xor(p, off, 64);          // butterfly: all lanes get sum

        const float mn = fmaxf(m, p);
        const float a  = __expf(m - mn);          // rescale old state
        const float w  = __expf(p - mn);          // this row's weight
        l = l * a + w;
        m = mn;
        o0.x = o0.x*a + w*x0.x;  o0.y = o0.y*a + w*x0.y;
        o0.z = o0.z*a + w*x0.z;  o0.w = o0.w*a + w*x0.w;
        o1.x = o1.x*a + w*x1.x;  o1.y = o1.y*a + w*x1.y;
        o1.z = o1.z*a + w*x1.z;  o1.w = o1.w*a + w*x1.w;
        o2.x = o2.x*a + w*x2.x;  o2.y = o2.y*a + w*x2.y;
        o2.z = o2.z*a + w*x2.z;  o2.w = o2.w*a + w*x2.w;
        o3.x = o3.x*a + w*x3.x;  o3.y = o3.y*a + w*x3.y;
        o3.z = o3.z*a + w*x3.z;  o3.w = o3.w*a + w*x3.w;
    }

    if (lane == 0) { sm[wid] = m; sl[wid] = l; }
    *(float4*)&so[wid][d0      ] = o0;
    *(float4*)&so[wid][d0 + 256] = o1;
    *(float4*)&so[wid][d0 + 512] = o2;
    *(float4*)&so[wid][d0 + 768] = o3;
    __syncthreads();

    // merge the 4 wave states (runs once per block; cost trivial)
    const float M  = fmaxf(fmaxf(sm[0], sm[1]), fmaxf(sm[2], sm[3]));
    const float e0 = __expf(sm[0] - M);
    const float e1 = __expf(sm[1] - M);
    const float e2 = __expf(sm[2] - M);
    const float e3 = __expf(sm[3] - M);
    const float L  = sl[0]*e0 + sl[1]*e1 + sl[2]*e2 + sl[3]*e3;

    const int dd = tid << 2;   // thread t now owns d = 4t..4t+3
    const float4 v0 = *(float4*)&so[0][dd];
    const float4 v1 = *(float4*)&so[1][dd];
    const float4 v2 = *(float4*)&so[2][dd];
    const float4 v3 = *(float4*)&so[3][dd];
    float4 acc;
    acc.x = v0.x*e0 + v1.x*e1 + v2.x*e2 + v3.x*e3;
    acc.y = v0.y*e0 + v1.y*e1 + v2.y*e2 + v3.y*e3;
    acc.z = v0.z*e0 + v1.z*e1 + v2.z*e2 + v3.z*e3;
    acc.w = v0.w*e0 + v1.w*e1 + v2.w*e2 + v3.w*e3;

    if (out_final) {
        const float inv = (L > 0.f) ? 1.f / L : 0.f;
        acc.x *= inv; acc.y *= inv; acc.z *= inv; acc.w *= inv;
        *(float4*)&out_final[(size_t)b * Dc + dd] = acc;
    } else {
        *(float4*)&o_part[((size_t)b * SPLIT + split) * Dc + dd] = acc;
        if (tid == 0) {
            ml_part[((size_t)b * SPLIT + split) * 2    ] = M;
            ml_part[((size_t)b * SPLIT + split) * 2 + 1] = L;
        }
    }
}

__global__ __launch_bounds__(256)
void attn_combine(const float* __restrict__ o_part,
                  const float* __restrict__ ml_part,
                  float* __restrict__ out, int SPLIT)
{
    __shared__ float sme[64], sle[64];
    const int b   = blockIdx.x;
    const int tid = threadIdx.x;
    if (tid < SPLIT) {
        sme[tid] = ml_part[((size_t)b * SPLIT + tid) * 2];
        sle[tid] = ml_part[((size_t)b * SPLIT + tid) * 2 + 1];
    }
    __syncthreads();

    float M = -INFINITY;
    for (int s = 0; s < SPLIT; ++s) M = fmaxf(M, sme[s]);
    float L = 0.f;
    for (int s = 0; s < SPLIT; ++s) L += sle[s] * __expf(sme[s] - M);

    const int dd = tid << 2;
    float4 acc = make_float4(0.f,0.f,0.f,0.f);
    for (int s = 0; s < SPLIT; ++s) {
        const float e = __expf(sme[s] - M);
        const float4 v = *(const float4*)&o_part[((size_t)b * SPLIT + s) * Dc + dd];
        acc.x += e * v.x; acc.y += e * v.y; acc.z += e * v.z; acc.w += e * v.w;
    }
    const float inv = (L > 0.f) ? 1.f / L : 0.f;
    acc.x *= inv; acc.y *= inv; acc.z *= inv; acc.w *= inv;
    *(float4*)&out[(size_t)b * Dc + dd] = acc;
}

extern "C" void kernel_launch(void* const* d_in, const int* in_sizes, int n_in,
                              void* d_out, int out_size, void* d_ws, size_t ws_size,
                              hipStream_t stream)
{
    const int*   mask = (const int*)d_in[0];    // bool mask, delivered as int32
    const float* enc  = (const float*)d_in[1];  // [B,S,D] fp32
    const float* hid  = (const float*)d_in[2];  // [B,D]   fp32
    float*       out  = (float*)d_out;          // [B,D]   fp32

    // choose largest split count whose partial buffers fit in d_ws
    int SPLIT = 32;
    while (SPLIT > 1 &&
           (size_t)Bc * SPLIT * (Dc + 2) * sizeof(float) > ws_size)
        SPLIT >>= 1;
    const bool direct =
        (SPLIT == 1) || ((size_t)Bc * (Dc + 2) * sizeof(float) > ws_size);
    if (direct) SPLIT = 1;

    float* o_part  = (float*)d_ws;
    float* ml_part = o_part + (size_t)Bc * SPLIT * Dc;

    attn_partial<<<dim3(SPLIT, Bc), 256, 0, stream>>>(
        mask, enc, hid,
        direct ? nullptr : o_part,
        direct ? nullptr : ml_part,
        direct ? out : nullptr,
        SPLIT, Sc / SPLIT);

    if (!direct)
        attn_combine<<<Bc, 256, 0, stream>>>(o_part, ml_part, out, SPLIT);
}